// Round 1
// baseline (549.796 us; speedup 1.0000x reference)
//
#include <hip/hip_runtime.h>

// OWA pooling: 2x2 non-overlapping window, per-channel descending sort (5-comparator
// network), weighted sum with 4 learned weights.
// x: [16,224,224,128] fp32 NHWC, out: [16,112,112,128] fp32.
// Pure streaming: 411 MB read + 103 MB write, zero reuse -> HBM roofline ~82 us.
//
// R4 changes vs R3:
//  - DROP nontemporal on loads AND stores. The harness re-poisons/restores buffers
//    right before the timed window, so input/output lines are L2/LLC-resident;
//    nt bypasses (evict-first) that residency and forces full HBM round trips.
//    Single-pass streaming has no reuse to protect, so nt had zero upside.
//  - Divisionless index decode via 3-D grid (7,112,16): blockIdx.y=ph, blockIdx.z=b,
//    lane bits give c4/pw. Removes the %112 // /112 magic-mul chains.
//    Same aggregate coalescing (16 full 64B lines per load instr), same 12,544 blocks.

typedef float vf4 __attribute__((ext_vector_type(4)));

#define B_    16
#define H_    224
#define W_    224
#define C_    128
#define PH_   (H_ / 2)            // 112
#define PW_   (W_ / 2)            // 112
#define C4_   (C_ / 4)            // 32 float4 per pixel
#define ROW4_ (W_ * C4_)          // 7168 float4 per input row
#define OROW4_ (PW_ * C4_)        // 3584 float4 per output row

__global__ __launch_bounds__(256) void owa_pool_kernel(
    const vf4* __restrict__ xin,
    const float* __restrict__ kw,
    vf4* __restrict__ out)
{
    const float k0 = kw[0], k1 = kw[1], k2 = kw[2], k3 = kw[3];

    const int c4  = threadIdx.x & 31;   // channel quad
    const int lpw = threadIdx.x >> 5;   // 0..7: output pixel within block chunk
    const int ph  = blockIdx.y;
    const int b   = blockIdx.z;

    const int in_row0  = (b * H_ + 2 * ph) * ROW4_;   // float4 index of input row 2*ph
    const int out_row  = (b * PH_ + ph) * OROW4_;     // float4 index of output row

    #pragma unroll
    for (int rep = 0; rep < 2; ++rep) {
        const int pw = blockIdx.x * 16 + rep * 8 + lpw;   // block covers 16 output pixels
        const int i0 = in_row0 + (2 * pw) * C4_ + c4;

        // 2x2 window at channel-quad c4 (cached loads: exploit LLC residency)
        vf4 v0 = xin[i0];                  // (2ph,   2pw)
        vf4 v1 = xin[i0 + C4_];            // (2ph,   2pw+1)
        vf4 v2 = xin[i0 + ROW4_];          // (2ph+1, 2pw)
        vf4 v3 = xin[i0 + ROW4_ + C4_];    // (2ph+1, 2pw+1)

        vf4 r;
        // 4-element descending sort network (5 comparators) + weighted sum
        #pragma unroll
        for (int comp = 0; comp < 4; ++comp) {
            float a0 = v0[comp], a1 = v1[comp], a2 = v2[comp], a3 = v3[comp];
            float hi01 = fmaxf(a0, a1), lo01 = fminf(a0, a1);
            float hi23 = fmaxf(a2, a3), lo23 = fminf(a2, a3);
            float s0 = fmaxf(hi01, hi23), m  = fminf(hi01, hi23);
            float M  = fmaxf(lo01, lo23), s3 = fminf(lo01, lo23);
            float s1 = fmaxf(m, M), s2 = fminf(m, M);
            r[comp] = k0 * s0 + k1 * s1 + k2 * s2 + k3 * s3;
        }

        out[out_row + pw * C4_ + c4] = r;
    }
}

extern "C" void kernel_launch(void* const* d_in, const int* in_sizes, int n_in,
                              void* d_out, int out_size, void* d_ws, size_t ws_size,
                              hipStream_t stream) {
    const vf4* xin = (const vf4*)d_in[0];
    const float* kw = (const float*)d_in[1];
    vf4* out = (vf4*)d_out;

    dim3 grid(PW_ / 16, PH_, B_);   // (7, 112, 16) = 12,544 blocks
    owa_pool_kernel<<<grid, 256, 0, stream>>>(xin, kw, out);
}

// Round 2
// 530.734 us; speedup vs baseline: 1.0359x; 1.0359x over previous
//
#include <hip/hip_runtime.h>

// OWA pooling: 2x2 non-overlapping window, per-channel descending sort (5-comparator
// network), weighted sum with 4 learned weights.
// x: [16,224,224,128] fp32 NHWC, out: [16,112,112,128] fp32.
// Pure streaming: 411 MB read + 103 MB write, zero reuse -> HBM roofline ~80 us.
//
// R5 = best of R3/R4:
//  - NON-TEMPORAL loads AND stores (R3). R4's A/B showed cached stores cost +19.6 us
//    = ~103-125 MB extra traffic = write-allocate/RFO on the output stream. nt stores
//    write-combine straight to HBM. nt loads: input (411 MB) exceeds the 256 MiB LLC,
//    so there is no residency to protect; evict-first costs nothing.
//  - Divisionless index decode via 3-D grid (7,112,16) (R4): blockIdx.y=ph,
//    blockIdx.z=b, lane bits give c4/pw. No %112 // /112 magic-mul chains.
//    Coalescing: per wave, v0 covers [X,X+512)+[X+1024,X+1536), v1 fills the gaps ->
//    2 KB fully-dense contiguous per load pair; stores 1 KB dense per wave.

typedef float vf4 __attribute__((ext_vector_type(4)));

#define B_    16
#define H_    224
#define W_    224
#define C_    128
#define PH_   (H_ / 2)            // 112
#define PW_   (W_ / 2)            // 112
#define C4_   (C_ / 4)            // 32 float4 per pixel
#define ROW4_ (W_ * C4_)          // 7168 float4 per input row
#define OROW4_ (PW_ * C4_)        // 3584 float4 per output row

__global__ __launch_bounds__(256) void owa_pool_kernel(
    const vf4* __restrict__ xin,
    const float* __restrict__ kw,
    vf4* __restrict__ out)
{
    const float k0 = kw[0], k1 = kw[1], k2 = kw[2], k3 = kw[3];

    const int c4  = threadIdx.x & 31;   // channel quad
    const int lpw = threadIdx.x >> 5;   // 0..7: output pixel within block chunk
    const int ph  = blockIdx.y;
    const int b   = blockIdx.z;

    const int in_row0 = (b * H_ + 2 * ph) * ROW4_;   // float4 index of input row 2*ph
    const int out_row = (b * PH_ + ph) * OROW4_;     // float4 index of output row

    #pragma unroll
    for (int rep = 0; rep < 2; ++rep) {
        const int pw = blockIdx.x * 16 + rep * 8 + lpw;   // block covers 16 output pixels
        const int i0 = in_row0 + (2 * pw) * C4_ + c4;

        // 2x2 window at channel-quad c4, streamed (non-temporal)
        vf4 v0 = __builtin_nontemporal_load(&xin[i0]);                 // (2ph,   2pw)
        vf4 v1 = __builtin_nontemporal_load(&xin[i0 + C4_]);           // (2ph,   2pw+1)
        vf4 v2 = __builtin_nontemporal_load(&xin[i0 + ROW4_]);         // (2ph+1, 2pw)
        vf4 v3 = __builtin_nontemporal_load(&xin[i0 + ROW4_ + C4_]);   // (2ph+1, 2pw+1)

        vf4 r;
        // 4-element descending sort network (5 comparators) + weighted sum
        #pragma unroll
        for (int comp = 0; comp < 4; ++comp) {
            float a0 = v0[comp], a1 = v1[comp], a2 = v2[comp], a3 = v3[comp];
            float hi01 = fmaxf(a0, a1), lo01 = fminf(a0, a1);
            float hi23 = fmaxf(a2, a3), lo23 = fminf(a2, a3);
            float s0 = fmaxf(hi01, hi23), m  = fminf(hi01, hi23);
            float M  = fmaxf(lo01, lo23), s3 = fminf(lo01, lo23);
            float s1 = fmaxf(m, M), s2 = fminf(m, M);
            r[comp] = k0 * s0 + k1 * s1 + k2 * s2 + k3 * s3;
        }

        __builtin_nontemporal_store(r, &out[out_row + pw * C4_ + c4]);
    }
}

extern "C" void kernel_launch(void* const* d_in, const int* in_sizes, int n_in,
                              void* d_out, int out_size, void* d_ws, size_t ws_size,
                              hipStream_t stream) {
    const vf4* xin = (const vf4*)d_in[0];
    const float* kw = (const float*)d_in[1];
    vf4* out = (vf4*)d_out;

    dim3 grid(PW_ / 16, PH_, B_);   // (7, 112, 16) = 12,544 blocks
    owa_pool_kernel<<<grid, 256, 0, stream>>>(xin, kw, out);
}